// Round 11
// baseline (925.440 us; speedup 1.0000x reference)
//
#include <hip/hip_runtime.h>
#include <hip/hip_bf16.h>

using bf16 = __hip_bfloat16;
typedef __attribute__((ext_vector_type(4))) float f4;
typedef __attribute__((ext_vector_type(16))) float f16v;
typedef __attribute__((ext_vector_type(8))) short s8v;
typedef __attribute__((ext_vector_type(4))) short s4v;
typedef __attribute__((ext_vector_type(4))) unsigned int u4v;
typedef unsigned int u32;

__device__ __forceinline__ short f2bf(float x) {
  bf16 h = __float2bfloat16(x);
  return *reinterpret_cast<short*>(&h);
}

__device__ __forceinline__ u32 pkbf(float lo, float hi) {
  return (u32)(unsigned short)f2bf(lo) | ((u32)(unsigned short)f2bf(hi) << 16);
}

__device__ __forceinline__ void gload16(const bf16* g, bf16* l) {
  __builtin_amdgcn_global_load_lds(
      (const __attribute__((address_space(1))) u32*)g,
      (__attribute__((address_space(3))) u32*)l, 16, 0, 0);
}

// ------------------------------------------------------------------
// merged fp32 -> bf16 for x, wq, wk, wv (one launch)
__global__ __launch_bounds__(256) void cvt_all(const float* __restrict__ x,
                                               const float* __restrict__ wq,
                                               const float* __restrict__ wk,
                                               const float* __restrict__ wv,
                                               bf16* __restrict__ xb,
                                               bf16* __restrict__ wqb,
                                               bf16* __restrict__ wkv) {
  const int bid = blockIdx.x;
  const float* s;
  bf16* d;
  size_t e;
  if (bid < 8192) {
    e = (((size_t)bid * 256) + threadIdx.x) << 3; s = x; d = xb;
  } else if (bid < 16384) {
    e = (((size_t)(bid - 8192) * 256) + threadIdx.x) << 3; s = wq; d = wqb;
  } else if (bid < 18432) {
    e = (((size_t)(bid - 16384) * 256) + threadIdx.x) << 3; s = wk; d = wkv;
  } else {
    e = (((size_t)(bid - 18432) * 256) + threadIdx.x) << 3; s = wv; d = wkv + 4194304;
  }
  f4 a = *(const f4*)(s + e);
  f4 b = *(const f4*)(s + e + 4);
  s8v r = { f2bf(a[0]), f2bf(a[1]), f2bf(a[2]), f2bf(a[3]),
            f2bf(b[0]), f2bf(b[1]), f2bf(b[2]), f2bf(b[3]) };
  *(s8v*)(d + e) = r;
}

// plain fp32 -> bf16 (for wo, launched after Q-gemm since wob aliases wqb)
__global__ __launch_bounds__(256) void cvt_bf16(const float* __restrict__ src,
                                                bf16* __restrict__ dst) {
  size_t e = ((size_t)blockIdx.x * 256 + threadIdx.x) << 3;
  f4 a = *(const f4*)(src + e);
  f4 b = *(const f4*)(src + e + 4);
  s8v r = { f2bf(a[0]), f2bf(a[1]), f2bf(a[2]), f2bf(a[3]),
            f2bf(b[0]), f2bf(b[1]), f2bf(b[2]), f2bf(b[3]) };
  *(s8v*)(dst + e) = r;
}

// merged cache converters: bid<4096 -> cache_k path, else cache_v transpose
__global__ __launch_bounds__(256) void cvt_cache(const float* __restrict__ ck,
                                                 const float* __restrict__ cv,
                                                 bf16* __restrict__ kfull,
                                                 bf16* __restrict__ vt) {
  const int bid = blockIdx.x;
  if (bid < 4096) {
    size_t e = ((size_t)bid * 256 + threadIdx.x) << 2;
    f4 v = *(const f4*)(ck + e);
    unsigned d = (unsigned)(e & 127u), p = (unsigned)((e >> 7) & 1023u), bk = (unsigned)(e >> 17);
    s4v r = { f2bf(v[0]), f2bf(v[1]), f2bf(v[2]), f2bf(v[3]) };
    *(s4v*)(kfull + (((size_t)bk * 2048 + p) << 7) + d) = r;
  } else {
    size_t e = ((size_t)(bid - 4096) * 256 + threadIdx.x) << 2;
    unsigned p = (unsigned)(e & 1023u), d = (unsigned)((e >> 10) & 127u), bk = (unsigned)(e >> 17);
    const float* s = cv + (((size_t)bk * 1024 + p) << 7) + d;
    s4v r = { f2bf(s[0]), f2bf(s[128]), f2bf(s[256]), f2bf(s[384]) };
    *(s4v*)(vt + (((size_t)bk * 128 + d) << 11) + p) = r;
  }
}

// ------------------------------------------------------------------
// merged in-place RoPE for Q (32768 blocks) and K (8192 blocks)
__device__ __forceinline__ void rope_body(bf16* buf, const float* fc,
                                          const float* fs, int sstride,
                                          int soff, size_t t) {
  unsigned ip = (unsigned)(t & 63u);
  unsigned s  = (unsigned)((t >> 6) & 1023u);
  unsigned hh = (unsigned)(t >> 16);
  size_t base = ((size_t)hh * sstride + soff + s) * 128 + 2 * ip;
  unsigned u = *(unsigned*)(buf + base);
  float xr = __uint_as_float(u << 16);
  float xi = __uint_as_float(u & 0xffff0000u);
  float c = fc[s * 64 + ip], sn = fs[s * 64 + ip];
  unsigned short r0 = (unsigned short)f2bf(xr * c - xi * sn);
  unsigned short r1 = (unsigned short)f2bf(xr * sn + xi * c);
  *(unsigned*)(buf + base) = (unsigned)r0 | ((unsigned)r1 << 16);
}

__global__ __launch_bounds__(256) void rope_all(bf16* __restrict__ q,
                                                bf16* __restrict__ k,
                                                const float* __restrict__ fc,
                                                const float* __restrict__ fs) {
  const int bid = blockIdx.x;
  if (bid < 32768)
    rope_body(q, fc, fs, 1024, 0, (size_t)bid * 256 + threadIdx.x);
  else
    rope_body(k, fc, fs, 2048, 1024, (size_t)(bid - 32768) * 256 + threadIdx.x);
}

// ------------------------------------------------------------------
// 256x256-tile GEMM, BK=64, 8-phase schedule (R4-proven distributed prefetch).
#define MODE_Q   0
#define MODE_OUT 1

#define PHASE_TAIL(AC, BC, KS, MH)                                           \
  {                                                                          \
    s8v af[4], bv[4];                                                        \
    const int cofs = ((((KS) * 4) | g) ^ fx) << 3;                           \
    _Pragma("unroll") for (int mi = 0; mi < 4; ++mi)                         \
        af[mi] = *(const s8v*)&(AC)[aRowBase + ((MH)*4 + mi) * 1024 + cofs]; \
    _Pragma("unroll") for (int ni = 0; ni < 4; ++ni)                         \
        bv[ni] = *(const s8v*)&(BC)[bRowBase + ni * 1024 + cofs];            \
    __builtin_amdgcn_s_barrier();                                            \
    asm volatile("s_waitcnt lgkmcnt(0)" ::: "memory");                       \
    __builtin_amdgcn_s_setprio(1);                                           \
    _Pragma("unroll") for (int mi = 0; mi < 4; ++mi)                         \
      _Pragma("unroll") for (int ni = 0; ni < 4; ++ni)                       \
          acc[(MH)*4 + mi][ni] = __builtin_amdgcn_mfma_f32_16x16x32_bf16(    \
              af[mi], bv[ni], acc[(MH)*4 + mi][ni], 0, 0, 0);                \
    __builtin_amdgcn_s_setprio(0);                                           \
    __builtin_amdgcn_s_barrier();                                            \
  }

#define PHASE_HEAD(AC, BC)                                                   \
  {                                                                          \
    __builtin_amdgcn_s_barrier();                                            \
    s8v af[4], bv[4];                                                        \
    const int cofs = (g ^ fx) << 3;                                          \
    _Pragma("unroll") for (int mi = 0; mi < 4; ++mi)                         \
        af[mi] = *(const s8v*)&(AC)[aRowBase + mi * 1024 + cofs];            \
    _Pragma("unroll") for (int ni = 0; ni < 4; ++ni)                         \
        bv[ni] = *(const s8v*)&(BC)[bRowBase + ni * 1024 + cofs];            \
    asm volatile("s_waitcnt lgkmcnt(0)" ::: "memory");                       \
    __builtin_amdgcn_s_setprio(1);                                           \
    _Pragma("unroll") for (int mi = 0; mi < 4; ++mi)                         \
      _Pragma("unroll") for (int ni = 0; ni < 4; ++ni)                       \
          acc[mi][ni] = __builtin_amdgcn_mfma_f32_16x16x32_bf16(             \
              af[mi], bv[ni], acc[mi][ni], 0, 0, 0);                         \
    __builtin_amdgcn_s_setprio(0);                                           \
    __builtin_amdgcn_s_barrier();                                            \
  }

#define KTILE(AC, BC, PA, PB, NA, NB, PF)                                    \
  {                                                                          \
    if (PF) { gload16((NA), (PA)); gload16((NA) + rstep, (PA) + 4096); }     \
    if (PF) asm volatile("s_waitcnt vmcnt(2)" ::: "memory");                 \
    else    asm volatile("s_waitcnt vmcnt(0)" ::: "memory");                 \
    PHASE_HEAD(AC, BC)                                                       \
    if (PF) { gload16((NA) + 2 * rstep, (PA) + 8192);                        \
              gload16((NA) + 3 * rstep, (PA) + 12288); }                     \
    PHASE_TAIL(AC, BC, 0, 1)                                                 \
    if (PF) { gload16((NB), (PB)); gload16((NB) + rstep, (PB) + 4096); }     \
    PHASE_TAIL(AC, BC, 1, 0)                                                 \
    if (PF) { gload16((NB) + 2 * rstep, (PB) + 8192);                        \
              gload16((NB) + 3 * rstep, (PB) + 12288); }                     \
    PHASE_TAIL(AC, BC, 1, 1)                                                 \
  }

template <int MODE>
__global__ __launch_bounds__(512, 2) void gemm256(const bf16* __restrict__ A,
                                                  const bf16* __restrict__ B,
                                                  void* __restrict__ o1,
                                                  int K, float scale) {
  extern __shared__ bf16 smem[];
  bf16* A0 = smem;
  bf16* A1 = smem + 16384;
  bf16* B0 = smem + 32768;
  bf16* B1 = smem + 49152;

  const int tid = threadIdx.x;
  const int lane = tid & 63;
  const int wid = tid >> 6;
  const int wm = wid >> 2, wn = wid & 3;
  const int fr = lane & 15;
  const int g = lane >> 4;
  const int rg = g << 2;
  const int fx = lane & 7;

  // XCD-bijective block swizzle (nwg % 8 == 0)
  const int gy = gridDim.y;
  int lin = blockIdx.y * gridDim.x + blockIdx.x;
  const int qq = (gridDim.x * gy) >> 3;
  lin = (lin & 7) * qq + (lin >> 3);
  const int bm = lin / gy;
  const int bn = lin % gy;

  const int r0 = tid >> 3;
  const int sc = (tid & 7) ^ (r0 & 7);
  const bf16* aptr = A + (size_t)(bm * 256 + r0) * K + sc * 8;
  const bf16* bptr = B + (size_t)(bn * 256 + r0) * K + sc * 8;
  const size_t rstep = (size_t)64 * K;
  const int wofs = (tid & 448) << 3;
  bf16* pA0 = A0 + wofs; bf16* pA1 = A1 + wofs;
  bf16* pB0 = B0 + wofs; bf16* pB1 = B1 + wofs;

  const int aRowBase = (wm * 128 + fr) * 64;
  const int bRowBase = (wn * 64 + fr) * 64;

  f4 acc[8][4] = {};

#pragma unroll
  for (int i = 0; i < 4; ++i) gload16(aptr + i * rstep, pA0 + i * 4096);
#pragma unroll
  for (int i = 0; i < 4; ++i) gload16(bptr + i * rstep, pB0 + i * 4096);

  const int nk = K >> 6;
  for (int kt = 0; kt < nk; kt += 2) {
    const bf16* na = aptr + (kt + 1) * 64;
    const bf16* nb = bptr + (kt + 1) * 64;
    KTILE(A0, B0, pA1, pB1, na, nb, true)
    const bool pf2 = (kt + 2 < nk);
    const bf16* na2 = aptr + (kt + 2) * 64;
    const bf16* nb2 = bptr + (kt + 2) * 64;
    KTILE(A1, B1, pA0, pB0, na2, nb2, pf2)
  }

#pragma unroll
  for (int m = 0; m < 8; ++m) {
    const int grow0 = bm * 256 + wm * 128 + m * 16 + rg;
    const int b = grow0 >> 10, s0 = grow0 & 1023;
#pragma unroll
    for (int n = 0; n < 4; ++n) {
      const int gcol = bn * 256 + wn * 64 + n * 16 + fr;
      if constexpr (MODE == MODE_OUT) {
#pragma unroll
        for (int j = 0; j < 4; ++j)
          ((float*)o1)[(size_t)(grow0 + j) * 4096 + gcol] = acc[m][n][j];
      } else {  // MODE_Q (scaled scatter to [b][h][s][d])
        const int h = gcol >> 7, d = gcol & 127;
#pragma unroll
        for (int j = 0; j < 4; ++j)
          ((bf16*)o1)[((((size_t)b * 32 + h) << 10) + s0 + j) * 128 + d] =
              __float2bfloat16(acc[m][n][j] * scale);
      }
    }
  }
}

// ------------------------------------------------------------------
// 128x256-tile GEMM for the KV projection (N=2048): grid 32x8 = 256 blocks.
#define PH128(AC, BC, KS, OPEN)                                              \
  {                                                                          \
    if (OPEN) __builtin_amdgcn_s_barrier();                                  \
    s8v af[4], bv[4];                                                        \
    const int cofs = ((((KS) * 4) | g) ^ fx) << 3;                           \
    _Pragma("unroll") for (int mi = 0; mi < 4; ++mi)                         \
        af[mi] = *(const s8v*)&(AC)[aRowBase + mi * 1024 + cofs];            \
    _Pragma("unroll") for (int ni = 0; ni < 4; ++ni)                         \
        bv[ni] = *(const s8v*)&(BC)[bRowBase + ni * 1024 + cofs];            \
    if (!(OPEN)) __builtin_amdgcn_s_barrier();                               \
    asm volatile("s_waitcnt lgkmcnt(0)" ::: "memory");                       \
    __builtin_amdgcn_s_setprio(1);                                           \
    _Pragma("unroll") for (int mi = 0; mi < 4; ++mi)                         \
      _Pragma("unroll") for (int ni = 0; ni < 4; ++ni)                       \
          acc[mi][ni] = __builtin_amdgcn_mfma_f32_16x16x32_bf16(             \
              af[mi], bv[ni], acc[mi][ni], 0, 0, 0);                         \
    __builtin_amdgcn_s_setprio(0);                                           \
    __builtin_amdgcn_s_barrier();                                            \
  }

#define KTILE128(AC, BC, PA, PB, NA, NB, PF)                                 \
  {                                                                          \
    if (PF) { gload16((NB), (PB)); gload16((NB) + rstep, (PB) + 4096); }     \
    if (PF) asm volatile("s_waitcnt vmcnt(2)" ::: "memory");                 \
    else    asm volatile("s_waitcnt vmcnt(0)" ::: "memory");                 \
    PH128(AC, BC, 0, true)                                                   \
    if (PF) { gload16((NB) + 2 * rstep, (PB) + 8192);                        \
              gload16((NB) + 3 * rstep, (PB) + 12288);                       \
              gload16((NA), (PA)); gload16((NA) + rstep, (PA) + 4096); }     \
    PH128(AC, BC, 1, false)                                                  \
  }

__global__ __launch_bounds__(512, 2) void gemm128kv(const bf16* __restrict__ A,
                                                    const bf16* __restrict__ B,
                                                    bf16* __restrict__ kout,
                                                    bf16* __restrict__ vout,
                                                    int K) {
  extern __shared__ bf16 smem[];
  bf16* A0 = smem;
  bf16* A1 = smem + 8192;
  bf16* B0 = smem + 16384;
  bf16* B1 = smem + 32768;

  const int tid = threadIdx.x;
  const int lane = tid & 63;
  const int wid = tid >> 6;
  const int wm = wid >> 2, wn = wid & 3;
  const int fr = lane & 15;
  const int g = lane >> 4;
  const int rg = g << 2;
  const int fx = lane & 7;

  const int gy = gridDim.y;
  int lin = blockIdx.y * gridDim.x + blockIdx.x;
  const int qq = (gridDim.x * gy) >> 3;
  lin = (lin & 7) * qq + (lin >> 3);
  const int bm = lin / gy;
  const int bn = lin % gy;

  const int r0 = tid >> 3;
  const int sc = (tid & 7) ^ (r0 & 7);
  const bf16* aptr = A + (size_t)(bm * 128 + r0) * K + sc * 8;
  const bf16* bptr = B + (size_t)(bn * 256 + r0) * K + sc * 8;
  const size_t rstep = (size_t)64 * K;
  const int wofs = (tid & 448) << 3;
  bf16* pA0 = A0 + wofs; bf16* pA1 = A1 + wofs;
  bf16* pB0 = B0 + wofs; bf16* pB1 = B1 + wofs;

  const int aRowBase = (wm * 64 + fr) * 64;
  const int bRowBase = (wn * 64 + fr) * 64;

  f4 acc[4][4] = {};

  gload16(aptr, pA0); gload16(aptr + rstep, pA0 + 4096);
#pragma unroll
  for (int i = 0; i < 4; ++i) gload16(bptr + i * rstep, pB0 + i * 4096);

  const int nk = K >> 6;
  for (int kt = 0; kt < nk; kt += 2) {
    const bf16* na = aptr + (kt + 1) * 64;
    const bf16* nb = bptr + (kt + 1) * 64;
    KTILE128(A0, B0, pA1, pB1, na, nb, true)
    const bool pf2 = (kt + 2 < nk);
    const bf16* na2 = aptr + (kt + 2) * 64;
    const bf16* nb2 = bptr + (kt + 2) * 64;
    KTILE128(A1, B1, pA0, pB0, na2, nb2, pf2)
  }

  // epilogue: cols 0..1023 = K proj, 1024..2047 = V proj (transposed write)
#pragma unroll
  for (int m = 0; m < 4; ++m) {
    const int grow0 = bm * 128 + wm * 64 + m * 16 + rg;
    const int b = grow0 >> 10, s0 = grow0 & 1023;
#pragma unroll
    for (int n = 0; n < 4; ++n) {
      const int gcol = bn * 256 + wn * 64 + n * 16 + fr;
      if (gcol < 1024) {
        const int hv = gcol >> 7, d = gcol & 127;
#pragma unroll
        for (int j = 0; j < 4; ++j)
          kout[(((size_t)b * 8 + hv) * 2048 + 1024 + s0 + j) * 128 + d] =
              __float2bfloat16(acc[m][n][j]);
      } else {
        const int c = gcol - 1024, hv = c >> 7, d = c & 127;
        s4v r = { f2bf(acc[m][n][0]), f2bf(acc[m][n][1]),
                  f2bf(acc[m][n][2]), f2bf(acc[m][n][3]) };
        *(s4v*)(vout + (((size_t)b * 8 + hv) * 128 + d) * 2048 + 1024 + s0) = r;
      }
    }
  }
}

// ------------------------------------------------------------------
// Flash attention (R10 structure: key-permuted swapped QK^T/PV, conflict-free
// 16-slot LDS, ones-MFMA row-sum). NEW: __launch_bounds__(512, 4) to get
// 2 blocks/CU — cross-block wave mixing hides exp2 chains + barrier drains.
__global__ __launch_bounds__(512, 4) void attn_kernel(const bf16* __restrict__ Q,
                                                      const bf16* __restrict__ Kf,
                                                      const bf16* __restrict__ Vt,
                                                      bf16* __restrict__ O) {
  __shared__ alignas(16) bf16 Kls[2][8192];
  __shared__ alignas(16) bf16 Vls[2][8192];

  const int tid = threadIdx.x;
  const int lane = tid & 63;
  const int w = tid >> 6;
  const int h = lane >> 5;
  const int q31 = lane & 31;
  // permuted key row: swap bits 2 and 3 of q31
  const int pq = (q31 & 19) | ((q31 & 4) << 1) | ((q31 & 8) >> 1);
  const int rxK = pq & 15;          // K read swizzle key (rows distinct mod 16)
  const int rowv = q31 >> 1;        // V read row' within 16-row subtile
  const int dpar = (q31 & 1) << 3;  // d parity -> slot bit 3

  int lin = blockIdx.y * 4 + blockIdx.x;               // 0..511
  lin = (lin & 7) * 64 + (lin >> 3);
  const int qb = lin & 3;
  const int hrem = (lin >> 2) & 3;
  const int pair = lin >> 4;                            // 0..31
  const int b = pair >> 3, kv = pair & 7;
  const int hd = kv * 4 + hrem;

  const size_t qbase = (((size_t)b * 32 + hd) << 10) * 128;
  const size_t kbase = (((size_t)b * 8 + kv) * 2048) * 128;
  const size_t vbase = (((size_t)b * 8 + kv) * 128) * 2048;

  const int qrow = qb * 256 + w * 32 + q31;
  s8v qf[8];
#pragma unroll
  for (int c = 0; c < 8; ++c)
    qf[c] = *(const s8v*)&Q[qbase + (size_t)qrow * 128 + c * 16 + h * 8];

  // ones A-fragment for the row-sum MFMA
  union { u32 u[4]; s8v v; } onesu;
#pragma unroll
  for (int i = 0; i < 4; ++i) onesu.u[i] = 0x3F803F80u;
  const s8v onesA = onesu.v;

  // staging: thread covers row (tid>>4) slot (tid&15); content chunk =
  // (tid&15) ^ ((tid>>4)&15). Pass 1 adds 32 rows (K: +32 keys, V: +64 d).
  const int sk = (tid >> 4) & 15;
  const int kch = (tid & 15) ^ sk;
  const int wbase = w * 512;
  const size_t vrow0 = (size_t)(2 * (tid >> 4) + (kch >> 3)) * 2048 + (kch & 7) * 8;

  f16v oacc[4] = {};
  f16v lacc = {};
  float mrun = -3e38f;

  auto stage = [&](int kb, int bufi) {
    const bf16* ksrc = Kf + kbase + (size_t)(kb * 64 + (tid >> 4)) * 128 + kch * 8;
    gload16(ksrc,            &Kls[bufi][wbase]);
    gload16(ksrc + 32 * 128, &Kls[bufi][4096 + wbase]);
    const bf16* vsrc = Vt + vbase + vrow0 + kb * 64;
    gload16(vsrc,             &Vls[bufi][wbase]);
    gload16(vsrc + 64 * 2048, &Vls[bufi][4096 + wbase]);
  };

  stage(0, 0);
  asm volatile("s_waitcnt vmcnt(0)" ::: "memory");
  __syncthreads();

  for (int kb = 0; kb < 32; ++kb) {
    const int bufi = kb & 1;
    if (kb + 1 < 32) stage(kb + 1, bufi ^ 1);

    const bf16* KB = Kls[bufi];
    const bf16* VB = Vls[bufi];

    // S^T = K[perm] . Q^T
    f16v sac[2] = {};
    __builtin_amdgcn_s_setprio(1);
#pragma unroll
    for (int c = 0; c < 8; ++c) {
      const int cc = 2 * c + h;
      const int cof = ((cc ^ rxK) << 3);
      s8v k0 = *(const s8v*)&KB[pq * 128 + cof];
      s8v k1 = *(const s8v*)&KB[(32 + pq) * 128 + cof];
      sac[0] = __builtin_amdgcn_mfma_f32_32x32x16_bf16(k0, qf[c], sac[0], 0, 0, 0);
      sac[1] = __builtin_amdgcn_mfma_f32_32x32x16_bf16(k1, qf[c], sac[1], 0, 0, 0);
    }
    __builtin_amdgcn_s_setprio(0);

    float pm = -3e38f;
#pragma unroll
    for (int r = 0; r < 16; ++r) {
      pm = fmaxf(pm, sac[0][r]);
      pm = fmaxf(pm, sac[1][r]);
    }
    pm = fmaxf(pm, __shfl_xor(pm, 32));

    const bool skip = __all(pm <= mrun + 8.0f);   // defer-max (T13)
    if (!skip) {
      const float mnew = fmaxf(mrun, pm);
      const float corr = exp2f(mrun - mnew);
      mrun = mnew;
#pragma unroll
      for (int r = 0; r < 16; ++r) lacc[r] *= corr;
#pragma unroll
      for (int m = 0; m < 4; ++m)
#pragma unroll
        for (int r = 0; r < 16; ++r) oacc[m][r] *= corr;
    }
#pragma unroll
    for (int s = 0; s < 2; ++s)
#pragma unroll
      for (int r = 0; r < 16; ++r)
        sac[s][r] = exp2f(sac[s][r] - mrun);

    // P -> bf16 B-frags: key permutation makes F[ksg] = 8 consecutive sacs.
    s8v F[4];
#pragma unroll
    for (int ksg = 0; ksg < 4; ++ksg) {
      const int s = ksg >> 1;
      const int u8 = (ksg & 1) << 3;
      union { u32 u[4]; s8v v; } fu;
#pragma unroll
      for (int t = 0; t < 4; ++t)
        fu.u[t] = pkbf(sac[s][u8 + 2 * t], sac[s][u8 + 2 * t + 1]);
      F[ksg] = fu.v;
    }

    __builtin_amdgcn_s_setprio(1);
#pragma unroll
    for (int ksg = 0; ksg < 4; ++ksg) {
      const int cc2 = 2 * ksg + h;
      const int vof = (((dpar | cc2) ^ rowv) << 3);
#pragma unroll
      for (int m = 0; m < 4; ++m) {
        s8v vf = *(const s8v*)&VB[(m * 16 + rowv) * 128 + vof];
        oacc[m] = __builtin_amdgcn_mfma_f32_32x32x16_bf16(vf, F[ksg], oacc[m], 0, 0, 0);
      }
      lacc = __builtin_amdgcn_mfma_f32_32x32x16_bf16(onesA, F[ksg], lacc, 0, 0, 0);
    }
    __builtin_amdgcn_s_setprio(0);

    asm volatile("s_waitcnt vmcnt(0)" ::: "memory");
    __syncthreads();
  }

  const float inv = 1.f / lacc[0];
  bf16* orow = O + ((size_t)b * 1024 + qrow) * 4096 + hd * 128;
#pragma unroll
  for (int m = 0; m < 4; ++m)
#pragma unroll
    for (int r = 0; r < 16; r += 2) {
      const int d = m * 32 + (r & 3) + 8 * (r >> 2) + 4 * h;
      *(u32*)&orow[d] = pkbf(oacc[m][r] * inv, oacc[m][r + 1] * inv);
    }
}

// ------------------------------------------------------------------
extern "C" void kernel_launch(void* const* d_in, const int* in_sizes, int n_in,
                              void* d_out, int out_size, void* d_ws, size_t ws_size,
                              hipStream_t stream) {
  const float* x  = (const float*)d_in[0];
  const float* fc = (const float*)d_in[1];
  const float* fs = (const float*)d_in[2];
  const float* ck = (const float*)d_in[3];
  const float* cv = (const float*)d_in[4];
  const float* wq = (const float*)d_in[5];
  const float* wk = (const float*)d_in[6];
  const float* wv = (const float*)d_in[7];
  const float* wo = (const float*)d_in[8];
  float* out = (float*)d_out;

  char* ws = (char*)d_ws;
  bf16* qr    = (bf16*)(ws);                     // [4][32][1024][128]  32 MiB
  bf16* kfull = (bf16*)(ws + (32u << 20));       // [4][8][2048][128]   16 MiB
  bf16* vt    = (bf16*)(ws + (48u << 20));       // [4][8][128][2048]   16 MiB
  bf16* xb    = (bf16*)(ws + (64u << 20));       // [4096][4096]        32 MiB
  bf16* attn  = xb;                              // aliases xb (dead by then)
  bf16* wqb   = (bf16*)(ws + (96u << 20));       // [4096][4096]        32 MiB
  bf16* wob   = wqb;                             // aliases wqb (dead by then)
  bf16* wkvb  = (bf16*)(ws + (128u << 20));      // [2048][4096]        16 MiB

  hipFuncSetAttribute(reinterpret_cast<const void*>(&gemm256<MODE_Q>),
                      hipFuncAttributeMaxDynamicSharedMemorySize, 131072);
  hipFuncSetAttribute(reinterpret_cast<const void*>(&gemm256<MODE_OUT>),
                      hipFuncAttributeMaxDynamicSharedMemorySize, 131072);
  hipFuncSetAttribute(reinterpret_cast<const void*>(&gemm128kv),
                      hipFuncAttributeMaxDynamicSharedMemorySize, 98304);

  cvt_all<<<20480, 256, 0, stream>>>(x, wq, wk, wv, xb, wqb, wkvb);
  cvt_cache<<<8192, 256, 0, stream>>>(ck, cv, kfull, vt);

  // Q scale = 1/sqrt(128) * log2(e)  (softmax computed in exp2 domain)
  gemm256<MODE_Q><<<dim3(16, 16), 512, 131072, stream>>>(
      xb, wqb, qr, 4096, 0.1275174198520337f);
  gemm128kv<<<dim3(32, 8), 512, 98304, stream>>>(xb, wkvb, kfull, vt, 4096);

  cvt_bf16<<<8192, 256, 0, stream>>>(wo, wob);   // after Q gemm: reuses wqb

  rope_all<<<40960, 256, 0, stream>>>(qr, kfull, fc, fs);

  attn_kernel<<<dim3(4, 128), 512, 0, stream>>>(qr, kfull, vt, attn);

  gemm256<MODE_OUT><<<dim3(16, 16), 512, 131072, stream>>>(
      attn, wob, out, 4096, 1.0f);
}

// Round 12
// 616.902 us; speedup vs baseline: 1.5001x; 1.5001x over previous
//
#include <hip/hip_runtime.h>
#include <hip/hip_bf16.h>

using bf16 = __hip_bfloat16;
typedef __attribute__((ext_vector_type(4))) float f4;
typedef __attribute__((ext_vector_type(16))) float f16v;
typedef __attribute__((ext_vector_type(8))) short s8v;
typedef __attribute__((ext_vector_type(4))) short s4v;
typedef __attribute__((ext_vector_type(4))) unsigned int u4v;
typedef unsigned int u32;

__device__ __forceinline__ short f2bf(float x) {
  bf16 h = __float2bfloat16(x);
  return *reinterpret_cast<short*>(&h);
}

__device__ __forceinline__ u32 pkbf(float lo, float hi) {
  return (u32)(unsigned short)f2bf(lo) | ((u32)(unsigned short)f2bf(hi) << 16);
}

__device__ __forceinline__ void gload16(const bf16* g, bf16* l) {
  __builtin_amdgcn_global_load_lds(
      (const __attribute__((address_space(1))) u32*)g,
      (__attribute__((address_space(3))) u32*)l, 16, 0, 0);
}

// ------------------------------------------------------------------
// merged fp32 -> bf16 for x, wq, wk, wv (one launch)
__global__ __launch_bounds__(256) void cvt_all(const float* __restrict__ x,
                                               const float* __restrict__ wq,
                                               const float* __restrict__ wk,
                                               const float* __restrict__ wv,
                                               bf16* __restrict__ xb,
                                               bf16* __restrict__ wqb,
                                               bf16* __restrict__ wkv) {
  const int bid = blockIdx.x;
  const float* s;
  bf16* d;
  size_t e;
  if (bid < 8192) {
    e = (((size_t)bid * 256) + threadIdx.x) << 3; s = x; d = xb;
  } else if (bid < 16384) {
    e = (((size_t)(bid - 8192) * 256) + threadIdx.x) << 3; s = wq; d = wqb;
  } else if (bid < 18432) {
    e = (((size_t)(bid - 16384) * 256) + threadIdx.x) << 3; s = wk; d = wkv;
  } else {
    e = (((size_t)(bid - 18432) * 256) + threadIdx.x) << 3; s = wv; d = wkv + 4194304;
  }
  f4 a = *(const f4*)(s + e);
  f4 b = *(const f4*)(s + e + 4);
  s8v r = { f2bf(a[0]), f2bf(a[1]), f2bf(a[2]), f2bf(a[3]),
            f2bf(b[0]), f2bf(b[1]), f2bf(b[2]), f2bf(b[3]) };
  *(s8v*)(d + e) = r;
}

// plain fp32 -> bf16 (for wo, launched after Q-gemm since wob aliases wqb)
__global__ __launch_bounds__(256) void cvt_bf16(const float* __restrict__ src,
                                                bf16* __restrict__ dst) {
  size_t e = ((size_t)blockIdx.x * 256 + threadIdx.x) << 3;
  f4 a = *(const f4*)(src + e);
  f4 b = *(const f4*)(src + e + 4);
  s8v r = { f2bf(a[0]), f2bf(a[1]), f2bf(a[2]), f2bf(a[3]),
            f2bf(b[0]), f2bf(b[1]), f2bf(b[2]), f2bf(b[3]) };
  *(s8v*)(dst + e) = r;
}

// merged cache converters: bid<4096 -> cache_k path, else cache_v transpose
__global__ __launch_bounds__(256) void cvt_cache(const float* __restrict__ ck,
                                                 const float* __restrict__ cv,
                                                 bf16* __restrict__ kfull,
                                                 bf16* __restrict__ vt) {
  const int bid = blockIdx.x;
  if (bid < 4096) {
    size_t e = ((size_t)bid * 256 + threadIdx.x) << 2;
    f4 v = *(const f4*)(ck + e);
    unsigned d = (unsigned)(e & 127u), p = (unsigned)((e >> 7) & 1023u), bk = (unsigned)(e >> 17);
    s4v r = { f2bf(v[0]), f2bf(v[1]), f2bf(v[2]), f2bf(v[3]) };
    *(s4v*)(kfull + (((size_t)bk * 2048 + p) << 7) + d) = r;
  } else {
    size_t e = ((size_t)(bid - 4096) * 256 + threadIdx.x) << 2;
    unsigned p = (unsigned)(e & 1023u), d = (unsigned)((e >> 10) & 127u), bk = (unsigned)(e >> 17);
    const float* s = cv + (((size_t)bk * 1024 + p) << 7) + d;
    s4v r = { f2bf(s[0]), f2bf(s[128]), f2bf(s[256]), f2bf(s[384]) };
    *(s4v*)(vt + (((size_t)bk * 128 + d) << 11) + p) = r;
  }
}

// ------------------------------------------------------------------
// merged in-place RoPE for Q (32768 blocks) and K (8192 blocks)
__device__ __forceinline__ void rope_body(bf16* buf, const float* fc,
                                          const float* fs, int sstride,
                                          int soff, size_t t) {
  unsigned ip = (unsigned)(t & 63u);
  unsigned s  = (unsigned)((t >> 6) & 1023u);
  unsigned hh = (unsigned)(t >> 16);
  size_t base = ((size_t)hh * sstride + soff + s) * 128 + 2 * ip;
  unsigned u = *(unsigned*)(buf + base);
  float xr = __uint_as_float(u << 16);
  float xi = __uint_as_float(u & 0xffff0000u);
  float c = fc[s * 64 + ip], sn = fs[s * 64 + ip];
  unsigned short r0 = (unsigned short)f2bf(xr * c - xi * sn);
  unsigned short r1 = (unsigned short)f2bf(xr * sn + xi * c);
  *(unsigned*)(buf + base) = (unsigned)r0 | ((unsigned)r1 << 16);
}

__global__ __launch_bounds__(256) void rope_all(bf16* __restrict__ q,
                                                bf16* __restrict__ k,
                                                const float* __restrict__ fc,
                                                const float* __restrict__ fs) {
  const int bid = blockIdx.x;
  if (bid < 32768)
    rope_body(q, fc, fs, 1024, 0, (size_t)bid * 256 + threadIdx.x);
  else
    rope_body(k, fc, fs, 2048, 1024, (size_t)(bid - 32768) * 256 + threadIdx.x);
}

// ------------------------------------------------------------------
// 256x256-tile GEMM, BK=64, 8-phase schedule (R4-proven distributed prefetch).
#define MODE_Q   0
#define MODE_OUT 1

#define PHASE_TAIL(AC, BC, KS, MH)                                           \
  {                                                                          \
    s8v af[4], bv[4];                                                        \
    const int cofs = ((((KS) * 4) | g) ^ fx) << 3;                           \
    _Pragma("unroll") for (int mi = 0; mi < 4; ++mi)                         \
        af[mi] = *(const s8v*)&(AC)[aRowBase + ((MH)*4 + mi) * 1024 + cofs]; \
    _Pragma("unroll") for (int ni = 0; ni < 4; ++ni)                         \
        bv[ni] = *(const s8v*)&(BC)[bRowBase + ni * 1024 + cofs];            \
    __builtin_amdgcn_s_barrier();                                            \
    asm volatile("s_waitcnt lgkmcnt(0)" ::: "memory");                       \
    __builtin_amdgcn_s_setprio(1);                                           \
    _Pragma("unroll") for (int mi = 0; mi < 4; ++mi)                         \
      _Pragma("unroll") for (int ni = 0; ni < 4; ++ni)                       \
          acc[(MH)*4 + mi][ni] = __builtin_amdgcn_mfma_f32_16x16x32_bf16(    \
              af[mi], bv[ni], acc[(MH)*4 + mi][ni], 0, 0, 0);                \
    __builtin_amdgcn_s_setprio(0);                                           \
    __builtin_amdgcn_s_barrier();                                            \
  }

#define PHASE_HEAD(AC, BC)                                                   \
  {                                                                          \
    __builtin_amdgcn_s_barrier();                                            \
    s8v af[4], bv[4];                                                        \
    const int cofs = (g ^ fx) << 3;                                          \
    _Pragma("unroll") for (int mi = 0; mi < 4; ++mi)                         \
        af[mi] = *(const s8v*)&(AC)[aRowBase + mi * 1024 + cofs];            \
    _Pragma("unroll") for (int ni = 0; ni < 4; ++ni)                         \
        bv[ni] = *(const s8v*)&(BC)[bRowBase + ni * 1024 + cofs];            \
    asm volatile("s_waitcnt lgkmcnt(0)" ::: "memory");                       \
    __builtin_amdgcn_s_setprio(1);                                           \
    _Pragma("unroll") for (int mi = 0; mi < 4; ++mi)                         \
      _Pragma("unroll") for (int ni = 0; ni < 4; ++ni)                       \
          acc[mi][ni] = __builtin_amdgcn_mfma_f32_16x16x32_bf16(             \
              af[mi], bv[ni], acc[mi][ni], 0, 0, 0);                         \
    __builtin_amdgcn_s_setprio(0);                                           \
    __builtin_amdgcn_s_barrier();                                            \
  }

#define KTILE(AC, BC, PA, PB, NA, NB, PF)                                    \
  {                                                                          \
    if (PF) { gload16((NA), (PA)); gload16((NA) + rstep, (PA) + 4096); }     \
    if (PF) asm volatile("s_waitcnt vmcnt(2)" ::: "memory");                 \
    else    asm volatile("s_waitcnt vmcnt(0)" ::: "memory");                 \
    PHASE_HEAD(AC, BC)                                                       \
    if (PF) { gload16((NA) + 2 * rstep, (PA) + 8192);                        \
              gload16((NA) + 3 * rstep, (PA) + 12288); }                     \
    PHASE_TAIL(AC, BC, 0, 1)                                                 \
    if (PF) { gload16((NB), (PB)); gload16((NB) + rstep, (PB) + 4096); }     \
    PHASE_TAIL(AC, BC, 1, 0)                                                 \
    if (PF) { gload16((NB) + 2 * rstep, (PB) + 8192);                        \
              gload16((NB) + 3 * rstep, (PB) + 12288); }                     \
    PHASE_TAIL(AC, BC, 1, 1)                                                 \
  }

template <int MODE>
__global__ __launch_bounds__(512, 2) void gemm256(const bf16* __restrict__ A,
                                                  const bf16* __restrict__ B,
                                                  void* __restrict__ o1,
                                                  int K, float scale) {
  extern __shared__ bf16 smem[];
  bf16* A0 = smem;
  bf16* A1 = smem + 16384;
  bf16* B0 = smem + 32768;
  bf16* B1 = smem + 49152;

  const int tid = threadIdx.x;
  const int lane = tid & 63;
  const int wid = tid >> 6;
  const int wm = wid >> 2, wn = wid & 3;
  const int fr = lane & 15;
  const int g = lane >> 4;
  const int rg = g << 2;
  const int fx = lane & 7;

  // XCD-bijective block swizzle (nwg % 8 == 0)
  const int gy = gridDim.y;
  int lin = blockIdx.y * gridDim.x + blockIdx.x;
  const int qq = (gridDim.x * gy) >> 3;
  lin = (lin & 7) * qq + (lin >> 3);
  const int bm = lin / gy;
  const int bn = lin % gy;

  const int r0 = tid >> 3;
  const int sc = (tid & 7) ^ (r0 & 7);
  const bf16* aptr = A + (size_t)(bm * 256 + r0) * K + sc * 8;
  const bf16* bptr = B + (size_t)(bn * 256 + r0) * K + sc * 8;
  const size_t rstep = (size_t)64 * K;
  const int wofs = (tid & 448) << 3;
  bf16* pA0 = A0 + wofs; bf16* pA1 = A1 + wofs;
  bf16* pB0 = B0 + wofs; bf16* pB1 = B1 + wofs;

  const int aRowBase = (wm * 128 + fr) * 64;
  const int bRowBase = (wn * 64 + fr) * 64;

  f4 acc[8][4] = {};

#pragma unroll
  for (int i = 0; i < 4; ++i) gload16(aptr + i * rstep, pA0 + i * 4096);
#pragma unroll
  for (int i = 0; i < 4; ++i) gload16(bptr + i * rstep, pB0 + i * 4096);

  const int nk = K >> 6;
  for (int kt = 0; kt < nk; kt += 2) {
    const bf16* na = aptr + (kt + 1) * 64;
    const bf16* nb = bptr + (kt + 1) * 64;
    KTILE(A0, B0, pA1, pB1, na, nb, true)
    const bool pf2 = (kt + 2 < nk);
    const bf16* na2 = aptr + (kt + 2) * 64;
    const bf16* nb2 = bptr + (kt + 2) * 64;
    KTILE(A1, B1, pA0, pB0, na2, nb2, pf2)
  }

#pragma unroll
  for (int m = 0; m < 8; ++m) {
    const int grow0 = bm * 256 + wm * 128 + m * 16 + rg;
    const int b = grow0 >> 10, s0 = grow0 & 1023;
#pragma unroll
    for (int n = 0; n < 4; ++n) {
      const int gcol = bn * 256 + wn * 64 + n * 16 + fr;
      if constexpr (MODE == MODE_OUT) {
#pragma unroll
        for (int j = 0; j < 4; ++j)
          ((float*)o1)[(size_t)(grow0 + j) * 4096 + gcol] = acc[m][n][j];
      } else {  // MODE_Q (scaled scatter to [b][h][s][d])
        const int h = gcol >> 7, d = gcol & 127;
#pragma unroll
        for (int j = 0; j < 4; ++j)
          ((bf16*)o1)[((((size_t)b * 32 + h) << 10) + s0 + j) * 128 + d] =
              __float2bfloat16(acc[m][n][j] * scale);
      }
    }
  }
}

// ------------------------------------------------------------------
// 128x256-tile GEMM for the KV projection (N=2048): grid 32x8 = 256 blocks.
#define PH128(AC, BC, KS, OPEN)                                              \
  {                                                                          \
    if (OPEN) __builtin_amdgcn_s_barrier();                                  \
    s8v af[4], bv[4];                                                        \
    const int cofs = ((((KS) * 4) | g) ^ fx) << 3;                           \
    _Pragma("unroll") for (int mi = 0; mi < 4; ++mi)                         \
        af[mi] = *(const s8v*)&(AC)[aRowBase + mi * 1024 + cofs];            \
    _Pragma("unroll") for (int ni = 0; ni < 4; ++ni)                         \
        bv[ni] = *(const s8v*)&(BC)[bRowBase + ni * 1024 + cofs];            \
    if (!(OPEN)) __builtin_amdgcn_s_barrier();                               \
    asm volatile("s_waitcnt lgkmcnt(0)" ::: "memory");                       \
    __builtin_amdgcn_s_setprio(1);                                           \
    _Pragma("unroll") for (int mi = 0; mi < 4; ++mi)                         \
      _Pragma("unroll") for (int ni = 0; ni < 4; ++ni)                       \
          acc[mi][ni] = __builtin_amdgcn_mfma_f32_16x16x32_bf16(             \
              af[mi], bv[ni], acc[mi][ni], 0, 0, 0);                         \
    __builtin_amdgcn_s_setprio(0);                                           \
    __builtin_amdgcn_s_barrier();                                            \
  }

#define KTILE128(AC, BC, PA, PB, NA, NB, PF)                                 \
  {                                                                          \
    if (PF) { gload16((NB), (PB)); gload16((NB) + rstep, (PB) + 4096); }     \
    if (PF) asm volatile("s_waitcnt vmcnt(2)" ::: "memory");                 \
    else    asm volatile("s_waitcnt vmcnt(0)" ::: "memory");                 \
    PH128(AC, BC, 0, true)                                                   \
    if (PF) { gload16((NB) + 2 * rstep, (PB) + 8192);                        \
              gload16((NB) + 3 * rstep, (PB) + 12288);                       \
              gload16((NA), (PA)); gload16((NA) + rstep, (PA) + 4096); }     \
    PH128(AC, BC, 1, false)                                                  \
  }

__global__ __launch_bounds__(512, 2) void gemm128kv(const bf16* __restrict__ A,
                                                    const bf16* __restrict__ B,
                                                    bf16* __restrict__ kout,
                                                    bf16* __restrict__ vout,
                                                    int K) {
  extern __shared__ bf16 smem[];
  bf16* A0 = smem;
  bf16* A1 = smem + 8192;
  bf16* B0 = smem + 16384;
  bf16* B1 = smem + 32768;

  const int tid = threadIdx.x;
  const int lane = tid & 63;
  const int wid = tid >> 6;
  const int wm = wid >> 2, wn = wid & 3;
  const int fr = lane & 15;
  const int g = lane >> 4;
  const int rg = g << 2;
  const int fx = lane & 7;

  const int gy = gridDim.y;
  int lin = blockIdx.y * gridDim.x + blockIdx.x;
  const int qq = (gridDim.x * gy) >> 3;
  lin = (lin & 7) * qq + (lin >> 3);
  const int bm = lin / gy;
  const int bn = lin % gy;

  const int r0 = tid >> 3;
  const int sc = (tid & 7) ^ (r0 & 7);
  const bf16* aptr = A + (size_t)(bm * 128 + r0) * K + sc * 8;
  const bf16* bptr = B + (size_t)(bn * 256 + r0) * K + sc * 8;
  const size_t rstep = (size_t)64 * K;
  const int wofs = (tid & 448) << 3;
  bf16* pA0 = A0 + wofs; bf16* pA1 = A1 + wofs;
  bf16* pB0 = B0 + wofs; bf16* pB1 = B1 + wofs;

  const int aRowBase = (wm * 64 + fr) * 64;
  const int bRowBase = (wn * 64 + fr) * 64;

  f4 acc[4][4] = {};

  gload16(aptr, pA0); gload16(aptr + rstep, pA0 + 4096);
#pragma unroll
  for (int i = 0; i < 4; ++i) gload16(bptr + i * rstep, pB0 + i * 4096);

  const int nk = K >> 6;
  for (int kt = 0; kt < nk; kt += 2) {
    const bf16* na = aptr + (kt + 1) * 64;
    const bf16* nb = bptr + (kt + 1) * 64;
    KTILE128(A0, B0, pA1, pB1, na, nb, true)
    const bool pf2 = (kt + 2 < nk);
    const bf16* na2 = aptr + (kt + 2) * 64;
    const bf16* nb2 = bptr + (kt + 2) * 64;
    KTILE128(A1, B1, pA0, pB0, na2, nb2, pf2)
  }

  // epilogue: cols 0..1023 = K proj, 1024..2047 = V proj (transposed write)
#pragma unroll
  for (int m = 0; m < 4; ++m) {
    const int grow0 = bm * 128 + wm * 64 + m * 16 + rg;
    const int b = grow0 >> 10, s0 = grow0 & 1023;
#pragma unroll
    for (int n = 0; n < 4; ++n) {
      const int gcol = bn * 256 + wn * 64 + n * 16 + fr;
      if (gcol < 1024) {
        const int hv = gcol >> 7, d = gcol & 127;
#pragma unroll
        for (int j = 0; j < 4; ++j)
          kout[(((size_t)b * 8 + hv) * 2048 + 1024 + s0 + j) * 128 + d] =
              __float2bfloat16(acc[m][n][j]);
      } else {
        const int c = gcol - 1024, hv = c >> 7, d = c & 127;
        s4v r = { f2bf(acc[m][n][0]), f2bf(acc[m][n][1]),
                  f2bf(acc[m][n][2]), f2bf(acc[m][n][3]) };
        *(s4v*)(vout + (((size_t)b * 8 + hv) * 128 + d) * 2048 + 1024 + s0) = r;
      }
    }
  }
}

// ------------------------------------------------------------------
// Flash attention (R10 structure: key-permuted swapped QK^T/PV, conflict-free
// 16-slot LDS, ones-MFMA row-sum). launch_bounds(512) — R11's (512,4) forced
// VGPR 96->64 and spilled accumulators to scratch (1.7 GB traffic, 2.5x
// slower). NEW vs R10: pairwise-tree running max (was a 32-deep fmax chain).
__global__ __launch_bounds__(512) void attn_kernel(const bf16* __restrict__ Q,
                                                   const bf16* __restrict__ Kf,
                                                   const bf16* __restrict__ Vt,
                                                   bf16* __restrict__ O) {
  __shared__ alignas(16) bf16 Kls[2][8192];
  __shared__ alignas(16) bf16 Vls[2][8192];

  const int tid = threadIdx.x;
  const int lane = tid & 63;
  const int w = tid >> 6;
  const int h = lane >> 5;
  const int q31 = lane & 31;
  // permuted key row: swap bits 2 and 3 of q31
  const int pq = (q31 & 19) | ((q31 & 4) << 1) | ((q31 & 8) >> 1);
  const int rxK = pq & 15;          // K read swizzle key (rows distinct mod 16)
  const int rowv = q31 >> 1;        // V read row' within 16-row subtile
  const int dpar = (q31 & 1) << 3;  // d parity -> slot bit 3

  int lin = blockIdx.y * 4 + blockIdx.x;               // 0..511
  lin = (lin & 7) * 64 + (lin >> 3);
  const int qb = lin & 3;
  const int hrem = (lin >> 2) & 3;
  const int pair = lin >> 4;                            // 0..31
  const int b = pair >> 3, kv = pair & 7;
  const int hd = kv * 4 + hrem;

  const size_t qbase = (((size_t)b * 32 + hd) << 10) * 128;
  const size_t kbase = (((size_t)b * 8 + kv) * 2048) * 128;
  const size_t vbase = (((size_t)b * 8 + kv) * 128) * 2048;

  const int qrow = qb * 256 + w * 32 + q31;
  s8v qf[8];
#pragma unroll
  for (int c = 0; c < 8; ++c)
    qf[c] = *(const s8v*)&Q[qbase + (size_t)qrow * 128 + c * 16 + h * 8];

  // ones A-fragment for the row-sum MFMA
  union { u32 u[4]; s8v v; } onesu;
#pragma unroll
  for (int i = 0; i < 4; ++i) onesu.u[i] = 0x3F803F80u;
  const s8v onesA = onesu.v;

  // staging: thread covers row (tid>>4) slot (tid&15); content chunk =
  // (tid&15) ^ ((tid>>4)&15). Pass 1 adds 32 rows (K: +32 keys, V: +64 d).
  const int sk = (tid >> 4) & 15;
  const int kch = (tid & 15) ^ sk;
  const int wbase = w * 512;
  const size_t vrow0 = (size_t)(2 * (tid >> 4) + (kch >> 3)) * 2048 + (kch & 7) * 8;

  f16v oacc[4] = {};
  f16v lacc = {};
  float mrun = -3e38f;

  auto stage = [&](int kb, int bufi) {
    const bf16* ksrc = Kf + kbase + (size_t)(kb * 64 + (tid >> 4)) * 128 + kch * 8;
    gload16(ksrc,            &Kls[bufi][wbase]);
    gload16(ksrc + 32 * 128, &Kls[bufi][4096 + wbase]);
    const bf16* vsrc = Vt + vbase + vrow0 + kb * 64;
    gload16(vsrc,             &Vls[bufi][wbase]);
    gload16(vsrc + 64 * 2048, &Vls[bufi][4096 + wbase]);
  };

  stage(0, 0);
  asm volatile("s_waitcnt vmcnt(0)" ::: "memory");
  __syncthreads();

  for (int kb = 0; kb < 32; ++kb) {
    const int bufi = kb & 1;
    if (kb + 1 < 32) stage(kb + 1, bufi ^ 1);

    const bf16* KB = Kls[bufi];
    const bf16* VB = Vls[bufi];

    // S^T = K[perm] . Q^T
    f16v sac[2] = {};
    __builtin_amdgcn_s_setprio(1);
#pragma unroll
    for (int c = 0; c < 8; ++c) {
      const int cc = 2 * c + h;
      const int cof = ((cc ^ rxK) << 3);
      s8v k0 = *(const s8v*)&KB[pq * 128 + cof];
      s8v k1 = *(const s8v*)&KB[(32 + pq) * 128 + cof];
      sac[0] = __builtin_amdgcn_mfma_f32_32x32x16_bf16(k0, qf[c], sac[0], 0, 0, 0);
      sac[1] = __builtin_amdgcn_mfma_f32_32x32x16_bf16(k1, qf[c], sac[1], 0, 0, 0);
    }
    __builtin_amdgcn_s_setprio(0);

    // pairwise-tree running max (depth 5, independent ops; was 32-dep chain)
    float mt[8];
#pragma unroll
    for (int r = 0; r < 8; ++r)
      mt[r] = fmaxf(fmaxf(sac[0][r], sac[0][r + 8]),
                    fmaxf(sac[1][r], sac[1][r + 8]));
#pragma unroll
    for (int s = 4; s > 0; s >>= 1)
#pragma unroll
      for (int r = 0; r < s; ++r) mt[r] = fmaxf(mt[r], mt[r + s]);
    float pm = fmaxf(mt[0], __shfl_xor(mt[0], 32));

    const bool skip = __all(pm <= mrun + 8.0f);   // defer-max (T13)
    if (!skip) {
      const float mnew = fmaxf(mrun, pm);
      const float corr = exp2f(mrun - mnew);
      mrun = mnew;
#pragma unroll
      for (int r = 0; r < 16; ++r) lacc[r] *= corr;
#pragma unroll
      for (int m = 0; m < 4; ++m)
#pragma unroll
        for (int r = 0; r < 16; ++r) oacc[m][r] *= corr;
    }
#pragma unroll
    for (int s = 0; s < 2; ++s)
#pragma unroll
      for (int r = 0; r < 16; ++r)
        sac[s][r] = exp2f(sac[s][r] - mrun);

    // P -> bf16 B-frags: key permutation makes F[ksg] = 8 consecutive sacs.
    s8v F[4];
#pragma unroll
    for (int ksg = 0; ksg < 4; ++ksg) {
      const int s = ksg >> 1;
      const int u8 = (ksg & 1) << 3;
      union { u32 u[4]; s8v v; } fu;
#pragma unroll
      for (int t = 0; t < 4; ++t)
        fu.u[t] = pkbf(sac[s][u8 + 2 * t], sac[s][u8 + 2 * t + 1]);
      F[ksg] = fu.v;
    }

    __builtin_amdgcn_s_setprio(1);
#pragma unroll
    for (int ksg = 0; ksg < 4; ++ksg) {
      const int cc2 = 2 * ksg + h;
      const int vof = (((dpar | cc2) ^ rowv) << 3);
#pragma unroll
      for (int m = 0; m < 4; ++m) {
        s8v vf = *(const s8v*)&VB[(m * 16 + rowv) * 128 + vof];
        oacc[m] = __builtin_amdgcn_mfma_f32_32x32x16_bf16(vf, F[ksg], oacc[m], 0, 0, 0);
      }
      lacc = __builtin_amdgcn_mfma_f32_32x32x16_bf16(onesA, F[ksg], lacc, 0, 0, 0);
    }
    __builtin_amdgcn_s_setprio(0);

    asm volatile("s_waitcnt vmcnt(0)" ::: "memory");
    __syncthreads();
  }

  const float inv = 1.f / lacc[0];
  bf16* orow = O + ((size_t)b * 1024 + qrow) * 4096 + hd * 128;
#pragma unroll
  for (int m = 0; m < 4; ++m)
#pragma unroll
    for (int r = 0; r < 16; r += 2) {
      const int d = m * 32 + (r & 3) + 8 * (r >> 2) + 4 * h;
      *(u32*)&orow[d] = pkbf(oacc[m][r] * inv, oacc[m][r + 1] * inv);
    }
}

// ------------------------------------------------------------------
extern "C" void kernel_launch(void* const* d_in, const int* in_sizes, int n_in,
                              void* d_out, int out_size, void* d_ws, size_t ws_size,
                              hipStream_t stream) {
  const float* x  = (const float*)d_in[0];
  const float* fc = (const float*)d_in[1];
  const float* fs = (const float*)d_in[2];
  const float* ck = (const float*)d_in[3];
  const float* cv = (const float*)d_in[4];
  const float* wq = (const float*)d_in[5];
  const float* wk = (const float*)d_in[6];
  const float* wv = (const float*)d_in[7];
  const float* wo = (const float*)d_in[8];
  float* out = (float*)d_out;

  char* ws = (char*)d_ws;
  bf16* qr    = (bf16*)(ws);                     // [4][32][1024][128]  32 MiB
  bf16* kfull = (bf16*)(ws + (32u << 20));       // [4][8][2048][128]   16 MiB
  bf16* vt    = (bf16*)(ws + (48u << 20));       // [4][8][128][2048]   16 MiB
  bf16* xb    = (bf16*)(ws + (64u << 20));       // [4096][4096]        32 MiB
  bf16* attn  = xb;                              // aliases xb (dead by then)
  bf16* wqb   = (bf16*)(ws + (96u << 20));       // [4096][4096]        32 MiB
  bf16* wob   = wqb;                             // aliases wqb (dead by then)
  bf16* wkvb  = (bf16*)(ws + (128u << 20));      // [2048][4096]        16 MiB

  hipFuncSetAttribute(reinterpret_cast<const void*>(&gemm256<MODE_Q>),
                      hipFuncAttributeMaxDynamicSharedMemorySize, 131072);
  hipFuncSetAttribute(reinterpret_cast<const void*>(&gemm256<MODE_OUT>),
                      hipFuncAttributeMaxDynamicSharedMemorySize, 131072);
  hipFuncSetAttribute(reinterpret_cast<const void*>(&gemm128kv),
                      hipFuncAttributeMaxDynamicSharedMemorySize, 98304);

  cvt_all<<<20480, 256, 0, stream>>>(x, wq, wk, wv, xb, wqb, wkvb);
  cvt_cache<<<8192, 256, 0, stream>>>(ck, cv, kfull, vt);

  // Q scale = 1/sqrt(128) * log2(e)  (softmax computed in exp2 domain)
  gemm256<MODE_Q><<<dim3(16, 16), 512, 131072, stream>>>(
      xb, wqb, qr, 4096, 0.1275174198520337f);
  gemm128kv<<<dim3(32, 8), 512, 98304, stream>>>(xb, wkvb, kfull, vt, 4096);

  cvt_bf16<<<8192, 256, 0, stream>>>(wo, wob);   // after Q gemm: reuses wqb

  rope_all<<<40960, 256, 0, stream>>>(qr, kfull, fc, fs);

  attn_kernel<<<dim3(4, 128), 512, 0, stream>>>(qr, kfull, vt, attn);

  gemm256<MODE_OUT><<<dim3(16, 16), 512, 131072, stream>>>(
      attn, wob, out, 4096, 1.0f);
}

// Round 13
// 616.063 us; speedup vs baseline: 1.5022x; 1.0014x over previous
//
#include <hip/hip_runtime.h>
#include <hip/hip_bf16.h>

using bf16 = __hip_bfloat16;
typedef __attribute__((ext_vector_type(4))) float f4;
typedef __attribute__((ext_vector_type(16))) float f16v;
typedef __attribute__((ext_vector_type(8))) short s8v;
typedef __attribute__((ext_vector_type(4))) short s4v;
typedef __attribute__((ext_vector_type(4))) unsigned int u4v;
typedef unsigned int u32;

__device__ __forceinline__ short f2bf(float x) {
  bf16 h = __float2bfloat16(x);
  return *reinterpret_cast<short*>(&h);
}

__device__ __forceinline__ u32 pkbf(float lo, float hi) {
  return (u32)(unsigned short)f2bf(lo) | ((u32)(unsigned short)f2bf(hi) << 16);
}

__device__ __forceinline__ void gload16(const bf16* g, bf16* l) {
  __builtin_amdgcn_global_load_lds(
      (const __attribute__((address_space(1))) u32*)g,
      (__attribute__((address_space(3))) u32*)l, 16, 0, 0);
}

// ------------------------------------------------------------------
// merged fp32 -> bf16 for x, wq, wk, wv (one launch)
__global__ __launch_bounds__(256) void cvt_all(const float* __restrict__ x,
                                               const float* __restrict__ wq,
                                               const float* __restrict__ wk,
                                               const float* __restrict__ wv,
                                               bf16* __restrict__ xb,
                                               bf16* __restrict__ wqb,
                                               bf16* __restrict__ wkv) {
  const int bid = blockIdx.x;
  const float* s;
  bf16* d;
  size_t e;
  if (bid < 8192) {
    e = (((size_t)bid * 256) + threadIdx.x) << 3; s = x; d = xb;
  } else if (bid < 16384) {
    e = (((size_t)(bid - 8192) * 256) + threadIdx.x) << 3; s = wq; d = wqb;
  } else if (bid < 18432) {
    e = (((size_t)(bid - 16384) * 256) + threadIdx.x) << 3; s = wk; d = wkv;
  } else {
    e = (((size_t)(bid - 18432) * 256) + threadIdx.x) << 3; s = wv; d = wkv + 4194304;
  }
  f4 a = *(const f4*)(s + e);
  f4 b = *(const f4*)(s + e + 4);
  s8v r = { f2bf(a[0]), f2bf(a[1]), f2bf(a[2]), f2bf(a[3]),
            f2bf(b[0]), f2bf(b[1]), f2bf(b[2]), f2bf(b[3]) };
  *(s8v*)(d + e) = r;
}

// plain fp32 -> bf16 (for wo, launched after Q-gemm since wob aliases wqb)
__global__ __launch_bounds__(256) void cvt_bf16(const float* __restrict__ src,
                                                bf16* __restrict__ dst) {
  size_t e = ((size_t)blockIdx.x * 256 + threadIdx.x) << 3;
  f4 a = *(const f4*)(src + e);
  f4 b = *(const f4*)(src + e + 4);
  s8v r = { f2bf(a[0]), f2bf(a[1]), f2bf(a[2]), f2bf(a[3]),
            f2bf(b[0]), f2bf(b[1]), f2bf(b[2]), f2bf(b[3]) };
  *(s8v*)(dst + e) = r;
}

// merged cache converters: bid<4096 -> cache_k path, else cache_v transpose
__global__ __launch_bounds__(256) void cvt_cache(const float* __restrict__ ck,
                                                 const float* __restrict__ cv,
                                                 bf16* __restrict__ kfull,
                                                 bf16* __restrict__ vt) {
  const int bid = blockIdx.x;
  if (bid < 4096) {
    size_t e = ((size_t)bid * 256 + threadIdx.x) << 2;
    f4 v = *(const f4*)(ck + e);
    unsigned d = (unsigned)(e & 127u), p = (unsigned)((e >> 7) & 1023u), bk = (unsigned)(e >> 17);
    s4v r = { f2bf(v[0]), f2bf(v[1]), f2bf(v[2]), f2bf(v[3]) };
    *(s4v*)(kfull + (((size_t)bk * 2048 + p) << 7) + d) = r;
  } else {
    size_t e = ((size_t)(bid - 4096) * 256 + threadIdx.x) << 2;
    unsigned p = (unsigned)(e & 1023u), d = (unsigned)((e >> 10) & 127u), bk = (unsigned)(e >> 17);
    const float* s = cv + (((size_t)bk * 1024 + p) << 7) + d;
    s4v r = { f2bf(s[0]), f2bf(s[128]), f2bf(s[256]), f2bf(s[384]) };
    *(s4v*)(vt + (((size_t)bk * 128 + d) << 11) + p) = r;
  }
}

// ------------------------------------------------------------------
// merged in-place RoPE for Q (32768 blocks) and K (8192 blocks)
__device__ __forceinline__ void rope_body(bf16* buf, const float* fc,
                                          const float* fs, int sstride,
                                          int soff, size_t t) {
  unsigned ip = (unsigned)(t & 63u);
  unsigned s  = (unsigned)((t >> 6) & 1023u);
  unsigned hh = (unsigned)(t >> 16);
  size_t base = ((size_t)hh * sstride + soff + s) * 128 + 2 * ip;
  unsigned u = *(unsigned*)(buf + base);
  float xr = __uint_as_float(u << 16);
  float xi = __uint_as_float(u & 0xffff0000u);
  float c = fc[s * 64 + ip], sn = fs[s * 64 + ip];
  unsigned short r0 = (unsigned short)f2bf(xr * c - xi * sn);
  unsigned short r1 = (unsigned short)f2bf(xr * sn + xi * c);
  *(unsigned*)(buf + base) = (unsigned)r0 | ((unsigned)r1 << 16);
}

__global__ __launch_bounds__(256) void rope_all(bf16* __restrict__ q,
                                                bf16* __restrict__ k,
                                                const float* __restrict__ fc,
                                                const float* __restrict__ fs) {
  const int bid = blockIdx.x;
  if (bid < 32768)
    rope_body(q, fc, fs, 1024, 0, (size_t)bid * 256 + threadIdx.x);
  else
    rope_body(k, fc, fs, 2048, 1024, (size_t)(bid - 32768) * 256 + threadIdx.x);
}

// ------------------------------------------------------------------
// 256x256-tile GEMM, BK=64, 8-phase schedule (R4-proven distributed prefetch).
#define MODE_Q   0
#define MODE_OUT 1

#define PHASE_TAIL(AC, BC, KS, MH)                                           \
  {                                                                          \
    s8v af[4], bv[4];                                                        \
    const int cofs = ((((KS) * 4) | g) ^ fx) << 3;                           \
    _Pragma("unroll") for (int mi = 0; mi < 4; ++mi)                         \
        af[mi] = *(const s8v*)&(AC)[aRowBase + ((MH)*4 + mi) * 1024 + cofs]; \
    _Pragma("unroll") for (int ni = 0; ni < 4; ++ni)                         \
        bv[ni] = *(const s8v*)&(BC)[bRowBase + ni * 1024 + cofs];            \
    __builtin_amdgcn_s_barrier();                                            \
    asm volatile("s_waitcnt lgkmcnt(0)" ::: "memory");                       \
    __builtin_amdgcn_s_setprio(1);                                           \
    _Pragma("unroll") for (int mi = 0; mi < 4; ++mi)                         \
      _Pragma("unroll") for (int ni = 0; ni < 4; ++ni)                       \
          acc[(MH)*4 + mi][ni] = __builtin_amdgcn_mfma_f32_16x16x32_bf16(    \
              af[mi], bv[ni], acc[(MH)*4 + mi][ni], 0, 0, 0);                \
    __builtin_amdgcn_s_setprio(0);                                           \
    __builtin_amdgcn_s_barrier();                                            \
  }

#define PHASE_HEAD(AC, BC)                                                   \
  {                                                                          \
    __builtin_amdgcn_s_barrier();                                            \
    s8v af[4], bv[4];                                                        \
    const int cofs = (g ^ fx) << 3;                                          \
    _Pragma("unroll") for (int mi = 0; mi < 4; ++mi)                         \
        af[mi] = *(const s8v*)&(AC)[aRowBase + mi * 1024 + cofs];            \
    _Pragma("unroll") for (int ni = 0; ni < 4; ++ni)                         \
        bv[ni] = *(const s8v*)&(BC)[bRowBase + ni * 1024 + cofs];            \
    asm volatile("s_waitcnt lgkmcnt(0)" ::: "memory");                       \
    __builtin_amdgcn_s_setprio(1);                                           \
    _Pragma("unroll") for (int mi = 0; mi < 4; ++mi)                         \
      _Pragma("unroll") for (int ni = 0; ni < 4; ++ni)                       \
          acc[mi][ni] = __builtin_amdgcn_mfma_f32_16x16x32_bf16(             \
              af[mi], bv[ni], acc[mi][ni], 0, 0, 0);                         \
    __builtin_amdgcn_s_setprio(0);                                           \
    __builtin_amdgcn_s_barrier();                                            \
  }

#define KTILE(AC, BC, PA, PB, NA, NB, PF)                                    \
  {                                                                          \
    if (PF) { gload16((NA), (PA)); gload16((NA) + rstep, (PA) + 4096); }     \
    if (PF) asm volatile("s_waitcnt vmcnt(2)" ::: "memory");                 \
    else    asm volatile("s_waitcnt vmcnt(0)" ::: "memory");                 \
    PHASE_HEAD(AC, BC)                                                       \
    if (PF) { gload16((NA) + 2 * rstep, (PA) + 8192);                        \
              gload16((NA) + 3 * rstep, (PA) + 12288); }                     \
    PHASE_TAIL(AC, BC, 0, 1)                                                 \
    if (PF) { gload16((NB), (PB)); gload16((NB) + rstep, (PB) + 4096); }     \
    PHASE_TAIL(AC, BC, 1, 0)                                                 \
    if (PF) { gload16((NB) + 2 * rstep, (PB) + 8192);                        \
              gload16((NB) + 3 * rstep, (PB) + 12288); }                     \
    PHASE_TAIL(AC, BC, 1, 1)                                                 \
  }

template <int MODE>
__global__ __launch_bounds__(512, 2) void gemm256(const bf16* __restrict__ A,
                                                  const bf16* __restrict__ B,
                                                  void* __restrict__ o1,
                                                  int K, float scale) {
  extern __shared__ bf16 smem[];
  bf16* A0 = smem;
  bf16* A1 = smem + 16384;
  bf16* B0 = smem + 32768;
  bf16* B1 = smem + 49152;

  const int tid = threadIdx.x;
  const int lane = tid & 63;
  const int wid = tid >> 6;
  const int wm = wid >> 2, wn = wid & 3;
  const int fr = lane & 15;
  const int g = lane >> 4;
  const int rg = g << 2;
  const int fx = lane & 7;

  // XCD-bijective block swizzle (nwg % 8 == 0)
  const int gy = gridDim.y;
  int lin = blockIdx.y * gridDim.x + blockIdx.x;
  const int qq = (gridDim.x * gy) >> 3;
  lin = (lin & 7) * qq + (lin >> 3);
  const int bm = lin / gy;
  const int bn = lin % gy;

  const int r0 = tid >> 3;
  const int sc = (tid & 7) ^ (r0 & 7);
  const bf16* aptr = A + (size_t)(bm * 256 + r0) * K + sc * 8;
  const bf16* bptr = B + (size_t)(bn * 256 + r0) * K + sc * 8;
  const size_t rstep = (size_t)64 * K;
  const int wofs = (tid & 448) << 3;
  bf16* pA0 = A0 + wofs; bf16* pA1 = A1 + wofs;
  bf16* pB0 = B0 + wofs; bf16* pB1 = B1 + wofs;

  const int aRowBase = (wm * 128 + fr) * 64;
  const int bRowBase = (wn * 64 + fr) * 64;

  f4 acc[8][4] = {};

#pragma unroll
  for (int i = 0; i < 4; ++i) gload16(aptr + i * rstep, pA0 + i * 4096);
#pragma unroll
  for (int i = 0; i < 4; ++i) gload16(bptr + i * rstep, pB0 + i * 4096);

  const int nk = K >> 6;
  for (int kt = 0; kt < nk; kt += 2) {
    const bf16* na = aptr + (kt + 1) * 64;
    const bf16* nb = bptr + (kt + 1) * 64;
    KTILE(A0, B0, pA1, pB1, na, nb, true)
    const bool pf2 = (kt + 2 < nk);
    const bf16* na2 = aptr + (kt + 2) * 64;
    const bf16* nb2 = bptr + (kt + 2) * 64;
    KTILE(A1, B1, pA0, pB0, na2, nb2, pf2)
  }

#pragma unroll
  for (int m = 0; m < 8; ++m) {
    const int grow0 = bm * 256 + wm * 128 + m * 16 + rg;
    const int b = grow0 >> 10, s0 = grow0 & 1023;
#pragma unroll
    for (int n = 0; n < 4; ++n) {
      const int gcol = bn * 256 + wn * 64 + n * 16 + fr;
      if constexpr (MODE == MODE_OUT) {
#pragma unroll
        for (int j = 0; j < 4; ++j)
          ((float*)o1)[(size_t)(grow0 + j) * 4096 + gcol] = acc[m][n][j];
      } else {  // MODE_Q (scaled scatter to [b][h][s][d])
        const int h = gcol >> 7, d = gcol & 127;
#pragma unroll
        for (int j = 0; j < 4; ++j)
          ((bf16*)o1)[((((size_t)b * 32 + h) << 10) + s0 + j) * 128 + d] =
              __float2bfloat16(acc[m][n][j] * scale);
      }
    }
  }
}

// ------------------------------------------------------------------
// 128x256-tile GEMM for the KV projection (N=2048): grid 32x8 = 256 blocks.
#define PH128(AC, BC, KS, OPEN)                                              \
  {                                                                          \
    if (OPEN) __builtin_amdgcn_s_barrier();                                  \
    s8v af[4], bv[4];                                                        \
    const int cofs = ((((KS) * 4) | g) ^ fx) << 3;                           \
    _Pragma("unroll") for (int mi = 0; mi < 4; ++mi)                         \
        af[mi] = *(const s8v*)&(AC)[aRowBase + mi * 1024 + cofs];            \
    _Pragma("unroll") for (int ni = 0; ni < 4; ++ni)                         \
        bv[ni] = *(const s8v*)&(BC)[bRowBase + ni * 1024 + cofs];            \
    if (!(OPEN)) __builtin_amdgcn_s_barrier();                               \
    asm volatile("s_waitcnt lgkmcnt(0)" ::: "memory");                       \
    __builtin_amdgcn_s_setprio(1);                                           \
    _Pragma("unroll") for (int mi = 0; mi < 4; ++mi)                         \
      _Pragma("unroll") for (int ni = 0; ni < 4; ++ni)                       \
          acc[mi][ni] = __builtin_amdgcn_mfma_f32_16x16x32_bf16(             \
              af[mi], bv[ni], acc[mi][ni], 0, 0, 0);                         \
    __builtin_amdgcn_s_setprio(0);                                           \
    __builtin_amdgcn_s_barrier();                                            \
  }

#define KTILE128(AC, BC, PA, PB, NA, NB, PF)                                 \
  {                                                                          \
    if (PF) { gload16((NB), (PB)); gload16((NB) + rstep, (PB) + 4096); }     \
    if (PF) asm volatile("s_waitcnt vmcnt(2)" ::: "memory");                 \
    else    asm volatile("s_waitcnt vmcnt(0)" ::: "memory");                 \
    PH128(AC, BC, 0, true)                                                   \
    if (PF) { gload16((NB) + 2 * rstep, (PB) + 8192);                        \
              gload16((NB) + 3 * rstep, (PB) + 12288);                       \
              gload16((NA), (PA)); gload16((NA) + rstep, (PA) + 4096); }     \
    PH128(AC, BC, 1, false)                                                  \
  }

__global__ __launch_bounds__(512, 2) void gemm128kv(const bf16* __restrict__ A,
                                                    const bf16* __restrict__ B,
                                                    bf16* __restrict__ kout,
                                                    bf16* __restrict__ vout,
                                                    int K) {
  extern __shared__ bf16 smem[];
  bf16* A0 = smem;
  bf16* A1 = smem + 8192;
  bf16* B0 = smem + 16384;
  bf16* B1 = smem + 32768;

  const int tid = threadIdx.x;
  const int lane = tid & 63;
  const int wid = tid >> 6;
  const int wm = wid >> 2, wn = wid & 3;
  const int fr = lane & 15;
  const int g = lane >> 4;
  const int rg = g << 2;
  const int fx = lane & 7;

  const int gy = gridDim.y;
  int lin = blockIdx.y * gridDim.x + blockIdx.x;
  const int qq = (gridDim.x * gy) >> 3;
  lin = (lin & 7) * qq + (lin >> 3);
  const int bm = lin / gy;
  const int bn = lin % gy;

  const int r0 = tid >> 3;
  const int sc = (tid & 7) ^ (r0 & 7);
  const bf16* aptr = A + (size_t)(bm * 128 + r0) * K + sc * 8;
  const bf16* bptr = B + (size_t)(bn * 256 + r0) * K + sc * 8;
  const size_t rstep = (size_t)64 * K;
  const int wofs = (tid & 448) << 3;
  bf16* pA0 = A0 + wofs; bf16* pA1 = A1 + wofs;
  bf16* pB0 = B0 + wofs; bf16* pB1 = B1 + wofs;

  const int aRowBase = (wm * 64 + fr) * 64;
  const int bRowBase = (wn * 64 + fr) * 64;

  f4 acc[4][4] = {};

  gload16(aptr, pA0); gload16(aptr + rstep, pA0 + 4096);
#pragma unroll
  for (int i = 0; i < 4; ++i) gload16(bptr + i * rstep, pB0 + i * 4096);

  const int nk = K >> 6;
  for (int kt = 0; kt < nk; kt += 2) {
    const bf16* na = aptr + (kt + 1) * 64;
    const bf16* nb = bptr + (kt + 1) * 64;
    KTILE128(A0, B0, pA1, pB1, na, nb, true)
    const bool pf2 = (kt + 2 < nk);
    const bf16* na2 = aptr + (kt + 2) * 64;
    const bf16* nb2 = bptr + (kt + 2) * 64;
    KTILE128(A1, B1, pA0, pB0, na2, nb2, pf2)
  }

  // epilogue: cols 0..1023 = K proj, 1024..2047 = V proj (transposed write)
#pragma unroll
  for (int m = 0; m < 4; ++m) {
    const int grow0 = bm * 128 + wm * 64 + m * 16 + rg;
    const int b = grow0 >> 10, s0 = grow0 & 1023;
#pragma unroll
    for (int n = 0; n < 4; ++n) {
      const int gcol = bn * 256 + wn * 64 + n * 16 + fr;
      if (gcol < 1024) {
        const int hv = gcol >> 7, d = gcol & 127;
#pragma unroll
        for (int j = 0; j < 4; ++j)
          kout[(((size_t)b * 8 + hv) * 2048 + 1024 + s0 + j) * 128 + d] =
              __float2bfloat16(acc[m][n][j]);
      } else {
        const int c = gcol - 1024, hv = c >> 7, d = c & 127;
        s4v r = { f2bf(acc[m][n][0]), f2bf(acc[m][n][1]),
                  f2bf(acc[m][n][2]), f2bf(acc[m][n][3]) };
        *(s4v*)(vout + (((size_t)b * 8 + hv) * 128 + d) * 2048 + 1024 + s0) = r;
      }
    }
  }
}

// ------------------------------------------------------------------
// Flash attention (R10 structure: key-permuted swapped QK^T/PV, conflict-free
// 16-slot LDS, ones-MFMA row-sum). launch_bounds(512) — R11's (512,4) forced
// VGPR 96->64 and spilled accumulators to scratch (1.7 GB traffic, 2.5x
// slower). NEW vs R10: pairwise-tree running max (was a 32-deep fmax chain).
__global__ __launch_bounds__(512) void attn_kernel(const bf16* __restrict__ Q,
                                                   const bf16* __restrict__ Kf,
                                                   const bf16* __restrict__ Vt,
                                                   bf16* __restrict__ O) {
  __shared__ alignas(16) bf16 Kls[2][8192];
  __shared__ alignas(16) bf16 Vls[2][8192];

  const int tid = threadIdx.x;
  const int lane = tid & 63;
  const int w = tid >> 6;
  const int h = lane >> 5;
  const int q31 = lane & 31;
  // permuted key row: swap bits 2 and 3 of q31
  const int pq = (q31 & 19) | ((q31 & 4) << 1) | ((q31 & 8) >> 1);
  const int rxK = pq & 15;          // K read swizzle key (rows distinct mod 16)
  const int rowv = q31 >> 1;        // V read row' within 16-row subtile
  const int dpar = (q31 & 1) << 3;  // d parity -> slot bit 3

  int lin = blockIdx.y * 4 + blockIdx.x;               // 0..511
  lin = (lin & 7) * 64 + (lin >> 3);
  const int qb = lin & 3;
  const int hrem = (lin >> 2) & 3;
  const int pair = lin >> 4;                            // 0..31
  const int b = pair >> 3, kv = pair & 7;
  const int hd = kv * 4 + hrem;

  const size_t qbase = (((size_t)b * 32 + hd) << 10) * 128;
  const size_t kbase = (((size_t)b * 8 + kv) * 2048) * 128;
  const size_t vbase = (((size_t)b * 8 + kv) * 128) * 2048;

  const int qrow = qb * 256 + w * 32 + q31;
  s8v qf[8];
#pragma unroll
  for (int c = 0; c < 8; ++c)
    qf[c] = *(const s8v*)&Q[qbase + (size_t)qrow * 128 + c * 16 + h * 8];

  // ones A-fragment for the row-sum MFMA
  union { u32 u[4]; s8v v; } onesu;
#pragma unroll
  for (int i = 0; i < 4; ++i) onesu.u[i] = 0x3F803F80u;
  const s8v onesA = onesu.v;

  // staging: thread covers row (tid>>4) slot (tid&15); content chunk =
  // (tid&15) ^ ((tid>>4)&15). Pass 1 adds 32 rows (K: +32 keys, V: +64 d).
  const int sk = (tid >> 4) & 15;
  const int kch = (tid & 15) ^ sk;
  const int wbase = w * 512;
  const size_t vrow0 = (size_t)(2 * (tid >> 4) + (kch >> 3)) * 2048 + (kch & 7) * 8;

  f16v oacc[4] = {};
  f16v lacc = {};
  float mrun = -3e38f;

  auto stage = [&](int kb, int bufi) {
    const bf16* ksrc = Kf + kbase + (size_t)(kb * 64 + (tid >> 4)) * 128 + kch * 8;
    gload16(ksrc,            &Kls[bufi][wbase]);
    gload16(ksrc + 32 * 128, &Kls[bufi][4096 + wbase]);
    const bf16* vsrc = Vt + vbase + vrow0 + kb * 64;
    gload16(vsrc,             &Vls[bufi][wbase]);
    gload16(vsrc + 64 * 2048, &Vls[bufi][4096 + wbase]);
  };

  stage(0, 0);
  asm volatile("s_waitcnt vmcnt(0)" ::: "memory");
  __syncthreads();

  for (int kb = 0; kb < 32; ++kb) {
    const int bufi = kb & 1;
    if (kb + 1 < 32) stage(kb + 1, bufi ^ 1);

    const bf16* KB = Kls[bufi];
    const bf16* VB = Vls[bufi];

    // S^T = K[perm] . Q^T
    f16v sac[2] = {};
    __builtin_amdgcn_s_setprio(1);
#pragma unroll
    for (int c = 0; c < 8; ++c) {
      const int cc = 2 * c + h;
      const int cof = ((cc ^ rxK) << 3);
      s8v k0 = *(const s8v*)&KB[pq * 128 + cof];
      s8v k1 = *(const s8v*)&KB[(32 + pq) * 128 + cof];
      sac[0] = __builtin_amdgcn_mfma_f32_32x32x16_bf16(k0, qf[c], sac[0], 0, 0, 0);
      sac[1] = __builtin_amdgcn_mfma_f32_32x32x16_bf16(k1, qf[c], sac[1], 0, 0, 0);
    }
    __builtin_amdgcn_s_setprio(0);

    // pairwise-tree running max (depth 5, independent ops; was 32-dep chain)
    float mt[8];
#pragma unroll
    for (int r = 0; r < 8; ++r)
      mt[r] = fmaxf(fmaxf(sac[0][r], sac[0][r + 8]),
                    fmaxf(sac[1][r], sac[1][r + 8]));
#pragma unroll
    for (int s = 4; s > 0; s >>= 1)
#pragma unroll
      for (int r = 0; r < s; ++r) mt[r] = fmaxf(mt[r], mt[r + s]);
    float pm = fmaxf(mt[0], __shfl_xor(mt[0], 32));

    const bool skip = __all(pm <= mrun + 8.0f);   // defer-max (T13)
    if (!skip) {
      const float mnew = fmaxf(mrun, pm);
      const float corr = exp2f(mrun - mnew);
      mrun = mnew;
#pragma unroll
      for (int r = 0; r < 16; ++r) lacc[r] *= corr;
#pragma unroll
      for (int m = 0; m < 4; ++m)
#pragma unroll
        for (int r = 0; r < 16; ++r) oacc[m][r] *= corr;
    }
#pragma unroll
    for (int s = 0; s < 2; ++s)
#pragma unroll
      for (int r = 0; r < 16; ++r)
        sac[s][r] = exp2f(sac[s][r] - mrun);

    // P -> bf16 B-frags: key permutation makes F[ksg] = 8 consecutive sacs.
    s8v F[4];
#pragma unroll
    for (int ksg = 0; ksg < 4; ++ksg) {
      const int s = ksg >> 1;
      const int u8 = (ksg & 1) << 3;
      union { u32 u[4]; s8v v; } fu;
#pragma unroll
      for (int t = 0; t < 4; ++t)
        fu.u[t] = pkbf(sac[s][u8 + 2 * t], sac[s][u8 + 2 * t + 1]);
      F[ksg] = fu.v;
    }

    __builtin_amdgcn_s_setprio(1);
#pragma unroll
    for (int ksg = 0; ksg < 4; ++ksg) {
      const int cc2 = 2 * ksg + h;
      const int vof = (((dpar | cc2) ^ rowv) << 3);
#pragma unroll
      for (int m = 0; m < 4; ++m) {
        s8v vf = *(const s8v*)&VB[(m * 16 + rowv) * 128 + vof];
        oacc[m] = __builtin_amdgcn_mfma_f32_32x32x16_bf16(vf, F[ksg], oacc[m], 0, 0, 0);
      }
      lacc = __builtin_amdgcn_mfma_f32_32x32x16_bf16(onesA, F[ksg], lacc, 0, 0, 0);
    }
    __builtin_amdgcn_s_setprio(0);

    asm volatile("s_waitcnt vmcnt(0)" ::: "memory");
    __syncthreads();
  }

  const float inv = 1.f / lacc[0];
  bf16* orow = O + ((size_t)b * 1024 + qrow) * 4096 + hd * 128;
#pragma unroll
  for (int m = 0; m < 4; ++m)
#pragma unroll
    for (int r = 0; r < 16; r += 2) {
      const int d = m * 32 + (r & 3) + 8 * (r >> 2) + 4 * h;
      *(u32*)&orow[d] = pkbf(oacc[m][r] * inv, oacc[m][r + 1] * inv);
    }
}

// ------------------------------------------------------------------
extern "C" void kernel_launch(void* const* d_in, const int* in_sizes, int n_in,
                              void* d_out, int out_size, void* d_ws, size_t ws_size,
                              hipStream_t stream) {
  const float* x  = (const float*)d_in[0];
  const float* fc = (const float*)d_in[1];
  const float* fs = (const float*)d_in[2];
  const float* ck = (const float*)d_in[3];
  const float* cv = (const float*)d_in[4];
  const float* wq = (const float*)d_in[5];
  const float* wk = (const float*)d_in[6];
  const float* wv = (const float*)d_in[7];
  const float* wo = (const float*)d_in[8];
  float* out = (float*)d_out;

  char* ws = (char*)d_ws;
  bf16* qr    = (bf16*)(ws);                     // [4][32][1024][128]  32 MiB
  bf16* kfull = (bf16*)(ws + (32u << 20));       // [4][8][2048][128]   16 MiB
  bf16* vt    = (bf16*)(ws + (48u << 20));       // [4][8][128][2048]   16 MiB
  bf16* xb    = (bf16*)(ws + (64u << 20));       // [4096][4096]        32 MiB
  bf16* attn  = xb;                              // aliases xb (dead by then)
  bf16* wqb   = (bf16*)(ws + (96u << 20));       // [4096][4096]        32 MiB
  bf16* wob   = wqb;                             // aliases wqb (dead by then)
  bf16* wkvb  = (bf16*)(ws + (128u << 20));      // [2048][4096]        16 MiB

  hipFuncSetAttribute(reinterpret_cast<const void*>(&gemm256<MODE_Q>),
                      hipFuncAttributeMaxDynamicSharedMemorySize, 131072);
  hipFuncSetAttribute(reinterpret_cast<const void*>(&gemm256<MODE_OUT>),
                      hipFuncAttributeMaxDynamicSharedMemorySize, 131072);
  hipFuncSetAttribute(reinterpret_cast<const void*>(&gemm128kv),
                      hipFuncAttributeMaxDynamicSharedMemorySize, 98304);

  cvt_all<<<20480, 256, 0, stream>>>(x, wq, wk, wv, xb, wqb, wkvb);
  cvt_cache<<<8192, 256, 0, stream>>>(ck, cv, kfull, vt);

  // Q scale = 1/sqrt(128) * log2(e)  (softmax computed in exp2 domain)
  gemm256<MODE_Q><<<dim3(16, 16), 512, 131072, stream>>>(
      xb, wqb, qr, 4096, 0.1275174198520337f);
  gemm128kv<<<dim3(32, 8), 512, 98304, stream>>>(xb, wkvb, kfull, vt, 4096);

  cvt_bf16<<<8192, 256, 0, stream>>>(wo, wob);   // after Q gemm: reuses wqb

  rope_all<<<40960, 256, 0, stream>>>(qr, kfull, fc, fs);

  attn_kernel<<<dim3(4, 128), 512, 0, stream>>>(qr, kfull, vt, attn);

  gemm256<MODE_OUT><<<dim3(16, 16), 512, 131072, stream>>>(
      attn, wob, out, 4096, 1.0f);
}